// Round 2
// baseline (567.050 us; speedup 1.0000x reference)
//
#include <hip/hip_runtime.h>

#define D 128
#define NT 128     // nodes per block (gemm)
#define KC 32      // K-chunk staged in LDS
#define GEMM_BLK 256

// ---------------------------------------------------------------------------
// Gather + mean aggregate: XA[i,:] = mean_j Z[neigh[i,j],:]
// One wave (64 lanes) per node; lane covers 2 columns via float2.
// Each neighbor row read is one coalesced 512B transaction per wave.
// ---------------------------------------------------------------------------
template<int S>
__global__ __launch_bounds__(256) void sage_gather(
    const float* __restrict__ Z, const int* __restrict__ neigh,
    float* __restrict__ XA, int N)
{
    const int wid  = (int)((blockIdx.x * blockDim.x + threadIdx.x) >> 6);
    const int lane = threadIdx.x & 63;
    if (wid >= N) return;
    const int* nb = neigh + (size_t)wid * S;
    float ax = 0.f, ay = 0.f;
#pragma unroll
    for (int j = 0; j < S; ++j) {
        const int r = nb[j];
        const float2 v = *(const float2*)(Z + (size_t)r * D + lane * 2);
        ax += v.x; ay += v.y;
    }
    const float inv = 1.0f / (float)S;
    float2 o; o.x = ax * inv; o.y = ay * inv;
    *(float2*)(XA + (size_t)wid * D + lane * 2) = o;
}

// ---------------------------------------------------------------------------
// Fused GEMM + bias + sigmoid + row L2-normalize.
// out[n,:] = l2norm(sigmoid([Xs[n,:] | Xa[n,:]] @ W + b)), W is [256,128].
// Block: 256 thr, 128 nodes, all 128 cols. Thread tile: 8 nodes x 8 cols.
// K staged in chunks of 32: XT (transposed X) + WL in LDS, ~33.8 KB total.
// In-place safe (Xs may alias out): all Xs reads complete (synced) before
// any epilogue store, and blocks own disjoint rows.
// ---------------------------------------------------------------------------
__global__ __launch_bounds__(GEMM_BLK, 3) void sage_gemm(
    const float* __restrict__ Xs, const float* __restrict__ Xa,
    const float* __restrict__ W,  const float* __restrict__ bias,
    float* __restrict__ out, int N)
{
    __shared__ float XT[KC][NT + 4];   // [32][132] transposed X chunk
    __shared__ float WL[KC][D + 4];    // [32][132] W chunk

    const int t      = threadIdx.x;
    const int block0 = blockIdx.x * NT;
    const int nb0 = (t >> 4) * 8;      // node offset 0..120
    const int cb0 = (t & 15) * 4;      // col base 0..60 (+64 for 2nd group)

    float acc[8][8];
#pragma unroll
    for (int n = 0; n < 8; ++n)
#pragma unroll
        for (int j = 0; j < 8; ++j) acc[n][j] = 0.f;

    const int kx = t & 31;             // X-staging: k index
    const int xg = t >> 5;             // 0..7
    const int wc4 = (t & 31) * 4;      // W-staging: col
    const int wk  = t >> 5;            // 0..7

    for (int c = 0; c < 8; ++c) {      // chunks 0..3 read Xs, 4..7 read Xa
        const float* __restrict__ src = (c < 4) ? (Xs + c * KC) : (Xa + (c - 4) * KC);

        // stage XT[k][node] (bank-balanced: b128 writes, coalesced b32 loads)
#pragma unroll
        for (int i = 0; i < 4; ++i) {
            const int nb4 = (xg + 8 * i) * 4;      // 0..124
            float v[4];
#pragma unroll
            for (int j = 0; j < 4; ++j) {
                const int gn = block0 + nb4 + j;
                v[j] = (gn < N) ? src[(size_t)gn * D + kx] : 0.f;
            }
            *(float4*)&XT[kx][nb4] = make_float4(v[0], v[1], v[2], v[3]);
        }
        // stage WL[k][col] (row-major, coalesced, conflict-free)
#pragma unroll
        for (int i = 0; i < 4; ++i) {
            const int k = wk + 8 * i;
            *(float4*)&WL[k][wc4] = *(const float4*)(W + (size_t)(c * KC + k) * D + wc4);
        }
        __syncthreads();

#pragma unroll 4
        for (int k = 0; k < KC; ++k) {
            const float4 x0 = *(const float4*)&XT[k][nb0];
            const float4 x1 = *(const float4*)&XT[k][nb0 + 4];
            const float4 w0 = *(const float4*)&WL[k][cb0];
            const float4 w1 = *(const float4*)&WL[k][cb0 + 64];
            const float xv[8] = {x0.x,x0.y,x0.z,x0.w,x1.x,x1.y,x1.z,x1.w};
            const float wv[8] = {w0.x,w0.y,w0.z,w0.w,w1.x,w1.y,w1.z,w1.w};
#pragma unroll
            for (int n = 0; n < 8; ++n)
#pragma unroll
                for (int j = 0; j < 8; ++j)
                    acc[n][j] = fmaf(xv[n], wv[j], acc[n][j]);
        }
        __syncthreads();
    }

    // epilogue: bias + sigmoid + L2 norm (reduce across 16-lane col groups)
    float b0v[4], b1v[4];
    *(float4*)b0v = *(const float4*)(bias + cb0);
    *(float4*)b1v = *(const float4*)(bias + 64 + cb0);
#pragma unroll
    for (int n = 0; n < 8; ++n) {
        float h[8]; float ss = 0.f;
#pragma unroll
        for (int j = 0; j < 4; ++j) {
            const float a = acc[n][j] + b0v[j];
            h[j] = 1.0f / (1.0f + __expf(-a));
        }
#pragma unroll
        for (int j = 0; j < 4; ++j) {
            const float a = acc[n][4 + j] + b1v[j];
            h[4 + j] = 1.0f / (1.0f + __expf(-a));
        }
#pragma unroll
        for (int j = 0; j < 8; ++j) ss += h[j] * h[j];
        ss += __shfl_xor(ss, 1);
        ss += __shfl_xor(ss, 2);
        ss += __shfl_xor(ss, 4);
        ss += __shfl_xor(ss, 8);
        const float inv = rsqrtf(ss);
        const int gn = block0 + nb0 + n;
        if (gn < N) {
            float4 o0 = make_float4(h[0]*inv, h[1]*inv, h[2]*inv, h[3]*inv);
            float4 o1 = make_float4(h[4]*inv, h[5]*inv, h[6]*inv, h[7]*inv);
            *(float4*)(out + (size_t)gn * D + cb0)      = o0;
            *(float4*)(out + (size_t)gn * D + 64 + cb0) = o1;
        }
    }
}

extern "C" void kernel_launch(void* const* d_in, const int* in_sizes, int n_in,
                              void* d_out, int out_size, void* d_ws, size_t ws_size,
                              hipStream_t stream) {
    const float* Z  = (const float*)d_in[0];
    const float* W0 = (const float*)d_in[1];
    const float* b0 = (const float*)d_in[2];
    const float* W1 = (const float*)d_in[3];
    const float* b1 = (const float*)d_in[4];
    const int*   n0 = (const int*)d_in[5];
    const int*   n1 = (const int*)d_in[6];
    float* out = (float*)d_out;
    const int N = in_sizes[0] / D;          // 100000

    float* XA = (float*)d_ws;               // N*D floats = 51.2 MB scratch

    const int gatherBlocks = (N + 3) / 4;   // 4 waves/block, 1 node/wave
    const int gemmBlocks   = (N + NT - 1) / NT;

    // layer 0 (S=25): aggregate Z -> XA; H0 written into d_out
    sage_gather<25><<<gatherBlocks, 256, 0, stream>>>(Z, n0, XA, N);
    sage_gemm<<<gemmBlocks, GEMM_BLK, 0, stream>>>(Z, XA, W0, b0, out, N);
    // layer 1 (S=10): aggregate H0 -> XA; final output in-place in d_out
    sage_gather<10><<<gatherBlocks, 256, 0, stream>>>(out, n1, XA, N);
    sage_gemm<<<gemmBlocks, GEMM_BLK, 0, stream>>>(out, XA, W1, b1, out, N);
}

// Round 5
// 337.266 us; speedup vs baseline: 1.6813x; 1.6813x over previous
//
#include <hip/hip_runtime.h>

typedef unsigned short u16;
typedef unsigned int   u32;
typedef __attribute__((ext_vector_type(8))) short short8;
typedef __attribute__((ext_vector_type(4))) float f32x4;

#define D 128
// ushort-index XOR swizzle: 16B-granule spread across banks (G4 / T2)
#define SWZ(idx, r) ((idx) ^ (((r) & 7) << 3))

__device__ __forceinline__ u16 f2bf(float x) {           // RNE fp32->bf16
    union { float f; u32 u; } v; v.f = x;
    u32 r = v.u + 0x7fffu + ((v.u >> 16) & 1u);
    return (u16)(r >> 16);
}

// ---------------------------------------------------------------------------
// Z fp32 -> bf16
// ---------------------------------------------------------------------------
__global__ __launch_bounds__(256) void convert_z(
    const float4* __restrict__ Z4, ushort4* __restrict__ Zb4, int n4)
{
    int i = blockIdx.x * 256 + threadIdx.x;
    if (i < n4) {
        float4 v = Z4[i];
        ushort4 u; u.x = f2bf(v.x); u.y = f2bf(v.y); u.z = f2bf(v.z); u.w = f2bf(v.w);
        Zb4[i] = u;
    }
}

// ---------------------------------------------------------------------------
// W [256][128] fp32 -> WT [128][256] bf16 (MFMA B-frags need k-contiguous)
// ---------------------------------------------------------------------------
__global__ __launch_bounds__(256) void transpose_w(
    const float* __restrict__ W, u16* __restrict__ WT)
{
    int t = blockIdx.x * 256 + threadIdx.x;
    if (t < 256 * 128) {
        int k = t >> 7, j = t & 127;
        WT[j * 256 + k] = f2bf(W[t]);
    }
}

// ---------------------------------------------------------------------------
// Gather+mean from a bf16 table (row stride `tstride` ushorts, 128 used).
// One wave per node; lane covers cols {2*lane, 2*lane+1} via one dword.
// ---------------------------------------------------------------------------
template<int S>
__global__ __launch_bounds__(256) void sage_gather_b(
    const u16* __restrict__ T, int tstride, const int* __restrict__ neigh,
    u16* __restrict__ XA, int N)
{
    int wid = (int)((blockIdx.x * 256 + threadIdx.x) >> 6);
    wid = __builtin_amdgcn_readfirstlane(wid);       // wave-uniform -> s_load idx
    const int lane = threadIdx.x & 63;
    if (wid >= N) return;
    const int* nb = neigh + (size_t)wid * S;
    float ax = 0.f, ay = 0.f;
#pragma unroll
    for (int j = 0; j < S; ++j) {
        const int r = nb[j];
        const u32 v = *(const u32*)(T + (size_t)r * tstride + lane * 2);
        union { u32 u; float f; } lo, hi;
        lo.u = v << 16; hi.u = v & 0xffff0000u;      // bf16 -> f32 exact
        ax += lo.f; ay += hi.f;
    }
    const float inv = 1.0f / (float)S;
    const u32 packed = ((u32)f2bf(ay * inv) << 16) | (u32)f2bf(ax * inv);
    *(u32*)(XA + (size_t)wid * D + lane * 2) = packed;
}

// ---------------------------------------------------------------------------
// Fused MFMA GEMM + bias + sigmoid + L2-normalize.
// out[n,:] = l2norm(sigmoid([Xs[n,:]|Xa[n,:]] @ W + b)),  K=256, Ncols=128.
// Block: 256 thr (4 waves), tile M=128. Wave w owns rows [32w,32w+32).
// LDS: XT[128][256]b16 (64KB, XOR-swizzled) + WT[128][256]b16 (64KB).
// MODE 0: Xs = fp32 Z (inline cvt), out = bf16 rows at stride 256 u16 (d_out).
// MODE 1: Xs = bf16 rows stride 256 u16 (Hb in d_out), out = fp32 (in-place:
//         block stages only its OWN rows before the sync, epilogue writes the
//         same rows -> no cross-block hazard).
// mfma_f32_16x16x32_bf16: C/D col=lane&15, row=(lane>>4)*4+reg [m89/m91];
// A/B frags: 8 k-contiguous bf16 per lane, k=(lane>>4)*8+i [m92 ladder].
// ---------------------------------------------------------------------------
template<int MODE>
__global__ __launch_bounds__(256) void sage_gemm_mfma(
    const void* __restrict__ Xs_, const u16* __restrict__ Xa,
    const u16* __restrict__ WTg, const float* __restrict__ bias,
    void* __restrict__ out_, int N)
{
    __shared__ __align__(16) u16 XT[128 * 256];   // 64KB
    __shared__ __align__(16) u16 WT[128 * 256];   // 64KB

    const int t = threadIdx.x;
    const int block0 = blockIdx.x * 128;

    // ---- stage Xs half (k = 0..127) ----
    if (MODE == 0) {
        const float* Xs = (const float*)Xs_;
#pragma unroll
        for (int i = 0; i < 16; ++i) {
            int c = t + i * 256, r = c >> 5, f4 = c & 31, gn = block0 + r;
            float4 v = make_float4(0.f, 0.f, 0.f, 0.f);
            if (gn < N) v = *(const float4*)(Xs + (size_t)gn * D + f4 * 4);
            ushort4 u; u.x = f2bf(v.x); u.y = f2bf(v.y); u.z = f2bf(v.z); u.w = f2bf(v.w);
            *(ushort4*)&XT[SWZ(r * 256 + f4 * 4, r)] = u;
        }
    } else {
        const u16* Xs = (const u16*)Xs_;          // row stride 256 u16
#pragma unroll
        for (int i = 0; i < 8; ++i) {
            int c = t + i * 256, r = c >> 4, o = c & 15, gn = block0 + r;
            uint4 v = make_uint4(0u, 0u, 0u, 0u);
            if (gn < N) v = *(const uint4*)(Xs + (size_t)gn * 256 + o * 8);
            *(uint4*)&XT[SWZ(r * 256 + o * 8, r)] = v;
        }
    }
    // ---- stage Xa half (k = 128..255) ----
#pragma unroll
    for (int i = 0; i < 8; ++i) {
        int c = t + i * 256, r = c >> 4, o = c & 15, gn = block0 + r;
        uint4 v = make_uint4(0u, 0u, 0u, 0u);
        if (gn < N) v = *(const uint4*)(Xa + (size_t)gn * D + o * 8);
        *(uint4*)&XT[SWZ(r * 256 + 128 + o * 8, r)] = v;
    }
    // ---- stage WT (all 128 j-rows x 256 k) ----
#pragma unroll
    for (int i = 0; i < 16; ++i) {
        int c = t + i * 256, r = c >> 5, o = c & 31;
        uint4 v = *(const uint4*)(WTg + r * 256 + o * 8);
        *(uint4*)&WT[SWZ(r * 256 + o * 8, r)] = v;
    }
    __syncthreads();

    // ---- MFMA: acc[mf][nf], 16 MFMAs per k-step, K/32 = 8 steps ----
    const int w = t >> 6, l = t & 63;
    const int l15 = l & 15, lq = l >> 4;
    f32x4 acc[2][8];
#pragma unroll
    for (int m = 0; m < 2; ++m)
#pragma unroll
        for (int n = 0; n < 8; ++n) acc[m][n] = (f32x4){0.f, 0.f, 0.f, 0.f};

#pragma unroll
    for (int ks = 0; ks < 8; ++ks) {
        const int ak = ks * 32 + lq * 8;
        const int r0 = w * 32 + l15, r1 = w * 32 + 16 + l15;
        short8 a0 = *(const short8*)&XT[SWZ(r0 * 256 + ak, r0)];
        short8 a1 = *(const short8*)&XT[SWZ(r1 * 256 + ak, r1)];
#pragma unroll
        for (int nf = 0; nf < 8; ++nf) {
            const int jr = nf * 16 + l15;
            short8 b = *(const short8*)&WT[SWZ(jr * 256 + ak, jr)];
            acc[0][nf] = __builtin_amdgcn_mfma_f32_16x16x32_bf16(a0, b, acc[0][nf], 0, 0, 0);
            acc[1][nf] = __builtin_amdgcn_mfma_f32_16x16x32_bf16(a1, b, acc[1][nf], 0, 0, 0);
        }
    }

    // ---- epilogue: bias + sigmoid + row L2-norm, via LDS for coalesced out ----
    float bs[8];
#pragma unroll
    for (int nf = 0; nf < 8; ++nf) bs[nf] = bias[nf * 16 + l15];

    __syncthreads();   // all MFMA LDS reads done before XT reuse
#pragma unroll
    for (int mf = 0; mf < 2; ++mf) {
#pragma unroll
        for (int rg = 0; rg < 4; ++rg) {
            const int r = w * 32 + mf * 16 + lq * 4 + rg;   // tile row
            float h[8]; float ss = 0.f;
#pragma unroll
            for (int nf = 0; nf < 8; ++nf) {
                const float a = acc[mf][nf][rg] + bs[nf];
                h[nf] = 1.0f / (1.0f + __expf(-a));
                ss += h[nf] * h[nf];
            }
            ss += __shfl_xor(ss, 1); ss += __shfl_xor(ss, 2);
            ss += __shfl_xor(ss, 4); ss += __shfl_xor(ss, 8);
            const float inv = rsqrtf(ss);
            if (MODE == 0) {
#pragma unroll
                for (int nf = 0; nf < 8; ++nf)
                    XT[r * 128 + nf * 16 + l15] = f2bf(h[nf] * inv);
            } else {
                float* OL = (float*)XT;                      // 128*128 f32 = 64KB
#pragma unroll
                for (int nf = 0; nf < 8; ++nf)
                    OL[r * 128 + nf * 16 + l15] = h[nf] * inv;
            }
        }
    }
    __syncthreads();

    if (MODE == 0) {            // bf16 rows at stride 256 u16 (half-used rows)
        u16* Hb = (u16*)out_;
#pragma unroll
        for (int i = 0; i < 8; ++i) {
            int c = t + i * 256, r = c >> 4, o = c & 15, gn = block0 + r;
            if (gn < N)
                *(uint4*)(Hb + (size_t)gn * 256 + o * 8) = *(const uint4*)&XT[r * 128 + o * 8];
        }
    } else {                    // fp32, stride 128 floats
        float* O = (float*)out_;
        const float* OL = (const float*)XT;
#pragma unroll
        for (int i = 0; i < 16; ++i) {
            int c = t + i * 256, r = c >> 5, o = c & 31, gn = block0 + r;
            if (gn < N)
                *(float4*)(O + (size_t)gn * D + o * 4) = *(const float4*)&OL[r * 128 + o * 4];
        }
    }
}

// ---------------------------------------------------------------------------
// ws layout (total exactly N*D*2*2 = 51.2MB, same footprint proven in R2):
//   [0, 25.6M)  : Zb (bf16 Z)        -- dead after gather25, then:
//     [0, 64K)    : W1T              (written after gather25)
//     [64K,128K)  : W0T
//     [128K, ..)  : XA1 (bf16, 25.6M; spills 128K into dead XA0 region)
//   [25.6M, 51.2M): XA0 (bf16)       -- dead after gemm0
// H0 lives in d_out as bf16 rows at 512B stride; gemm1 overwrites in place.
// ---------------------------------------------------------------------------
extern "C" void kernel_launch(void* const* d_in, const int* in_sizes, int n_in,
                              void* d_out, int out_size, void* d_ws, size_t ws_size,
                              hipStream_t stream) {
    const float* Z  = (const float*)d_in[0];
    const float* W0 = (const float*)d_in[1];
    const float* b0 = (const float*)d_in[2];
    const float* W1 = (const float*)d_in[3];
    const float* b1 = (const float*)d_in[4];
    const int*   n0 = (const int*)d_in[5];
    const int*   n1 = (const int*)d_in[6];
    const int N = in_sizes[0] / D;                     // 100000

    const size_t zbBytes = (size_t)N * D * 2;          // 25.6 MB
    u16* Zb  = (u16*)d_ws;
    u16* XA0 = (u16*)((char*)d_ws + zbBytes);
    u16* W1T = (u16*)d_ws;
    u16* W0T = (u16*)((char*)d_ws + 65536);
    u16* XA1 = (u16*)((char*)d_ws + 131072);
    u16* Hb  = (u16*)d_out;
    float* out = (float*)d_out;

    const int n4 = (N * D) / 4;
    const int cvtBlocks    = (n4 + 255) / 256;
    const int gatherBlocks = (N + 3) / 4;
    const int gemmBlocks   = (N + 127) / 128;

    convert_z<<<cvtBlocks, 256, 0, stream>>>((const float4*)Z, (ushort4*)Zb, n4);
    sage_gather_b<25><<<gatherBlocks, 256, 0, stream>>>(Zb, 128, n0, XA0, N);
    transpose_w<<<128, 256, 0, stream>>>(W1, W1T);     // Zb dead from here
    transpose_w<<<128, 256, 0, stream>>>(W0, W0T);
    sage_gemm_mfma<0><<<gemmBlocks, 256, 0, stream>>>((const void*)Z, XA0, W0T, b0, (void*)Hb, N);
    sage_gather_b<10><<<gatherBlocks, 256, 0, stream>>>(Hb, 256, n1, XA1, N);
    sage_gemm_mfma<1><<<gemmBlocks, 256, 0, stream>>>((const void*)Hb, XA1, W1T, b1, (void*)out, N);
}

// Round 8
// 317.124 us; speedup vs baseline: 1.7881x; 1.0635x over previous
//
#include <hip/hip_runtime.h>

typedef unsigned short u16;
typedef unsigned int   u32;
typedef __attribute__((ext_vector_type(8))) short short8;
typedef __attribute__((ext_vector_type(4))) float f32x4;

#define D 128
// u16-index XOR swizzle, 16B granules (bits 3..5) spread by row (G4 / T2)
#define SWZ(idx, r)  ((idx) ^ (((r) & 7) << 3))
// f32-index XOR swizzle, 16B granules (bits 2..4)
#define SWZF(idx, r) ((idx) ^ (((r) & 7) << 2))

__device__ __forceinline__ u16 f2bf(float x) {           // RNE fp32->bf16
    union { float f; u32 u; } v; v.f = x;
    u32 r = v.u + 0x7fffu + ((v.u >> 16) & 1u);
    return (u16)(r >> 16);
}

// ---------------------------------------------------------------------------
// Z fp32 -> bf16 (feeds both gather25's table and gemm0's B-fragments)
// ---------------------------------------------------------------------------
__global__ __launch_bounds__(256) void convert_z(
    const float4* __restrict__ Z4, ushort4* __restrict__ Zb4, int n4)
{
    int i = blockIdx.x * 256 + threadIdx.x;
    if (i < n4) {
        float4 v = Z4[i];
        ushort4 u; u.x = f2bf(v.x); u.y = f2bf(v.y); u.z = f2bf(v.z); u.w = f2bf(v.w);
        Zb4[i] = u;
    }
}

// ---------------------------------------------------------------------------
// Gather+mean from a bf16 table (row stride `tstride` u16, 128 used).
// One wave per node (wave-uniform index -> s_load'ed neighbor list).
// Measured R5: 83us, 46% HBM, 0 bank conflicts -- unchanged this round.
// ---------------------------------------------------------------------------
template<int S>
__global__ __launch_bounds__(256) void sage_gather_b(
    const u16* __restrict__ T, int tstride, const int* __restrict__ neigh,
    u16* __restrict__ XA, int N)
{
    int wid = (int)((blockIdx.x * 256 + threadIdx.x) >> 6);
    wid = __builtin_amdgcn_readfirstlane(wid);
    const int lane = threadIdx.x & 63;
    if (wid >= N) return;
    const int* nb = neigh + (size_t)wid * S;
    float ax = 0.f, ay = 0.f;
#pragma unroll
    for (int j = 0; j < S; ++j) {
        const int r = nb[j];
        const u32 v = *(const u32*)(T + (size_t)r * tstride + lane * 2);
        union { u32 u; float f; } lo, hi;
        lo.u = v << 16; hi.u = v & 0xffff0000u;
        ax += lo.f; ay += hi.f;
    }
    const float inv = 1.0f / (float)S;
    const u32 packed = ((u32)f2bf(ay * inv) << 16) | (u32)f2bf(ax * inv);
    *(u32*)(XA + (size_t)wid * D + lane * 2) = packed;
}

// ---------------------------------------------------------------------------
// Fused MFMA GEMM + bias + sigmoid + L2-normalize.  K=256, 128 out cols.
// A-operand = W^T j-rows (LDS, 64KB, built in-kernel -> no transpose kernel),
// B-operand = X node-rows DIRECT FROM GLOBAL into registers (k-contiguous
// in memory, so no LDS staging for X). 64KB LDS -> 2 blocks/CU.
//   D[j][n]: C/D col(lane&15)=node n (B free dim), row((lane>>4)*4+reg)=j.
//   A-frag: lane l holds W^T row j=l&15, k=(l>>4)*8+i  (from LDS, swizzled)
//   B-frag: lane l holds X row n=l&15, k=(l>>4)*8+i    (16B global load)
// Xs rows: stride xs_stride u16, k=0..127; Xa rows: 128 u16, k=128..255.
// MODE 0: out = bf16 rows at stride 256 u16 (Hb in d_out).
// MODE 1: out = fp32 dense [N][128], in-place over Hb (block reads only its
//         own rows before its epilogue writes them; rows disjoint across
//         blocks -> no cross-block hazard; tail-clamp reads stay in-block).
// ---------------------------------------------------------------------------
template<int MODE>
__global__ __launch_bounds__(256) void sage_gemm_mfma(
    const u16* __restrict__ Xs, int xs_stride, const u16* __restrict__ Xa,
    const float* __restrict__ W, const float* __restrict__ bias,
    void* __restrict__ out_, int N)
{
    __shared__ __align__(16) u16 WT[128 * 256];   // 64KB: W^T bf16, swizzled

    const int t = threadIdx.x;
    const int block0 = blockIdx.x * 128;
    const int w = t >> 6, l = t & 63;
    const int l15 = l & 15, lq = l >> 4;

    // wave w owns nodes [w*32, w*32+32); clamp OOB rows (writes guarded later)
    const int row0 = min(block0 + w * 32 + l15,      N - 1);
    const int row1 = min(block0 + w * 32 + 16 + l15, N - 1);

    // ---- issue B-frags for mf=0 now; latency hides under W staging ----
    short8 b0[8];
#pragma unroll
    for (int ks = 0; ks < 8; ++ks) {
        const int k0 = ks * 32 + lq * 8;
        const u16* p = (ks < 4) ? (Xs + (size_t)row0 * xs_stride + k0)
                                : (Xa + (size_t)row0 * 128 + (k0 - 128));
        b0[ks] = *(const short8*)p;
    }

    // ---- stage W [256][128] fp32 -> WT[j][k] bf16, swizzled ----
    {
        const int j = t & 127, g = t >> 7;          // g = 0,1 (k half)
#pragma unroll
        for (int kk = 0; kk < 64; ++kk) {
            const int k = g * 128 + kk * 2;
            const float wa = W[(size_t)k * 128 + j];        // coalesced in j
            const float wb = W[(size_t)(k + 1) * 128 + j];
            const u32 pk = ((u32)f2bf(wb) << 16) | (u32)f2bf(wa);
            *(u32*)&WT[SWZ(j * 256 + k, j)] = pk;           // ~8-way b32, cheap
        }
    }
    __syncthreads();

    f32x4 acc[2][8];
#pragma unroll
    for (int m = 0; m < 2; ++m)
#pragma unroll
        for (int n = 0; n < 8; ++n) acc[m][n] = (f32x4){0.f, 0.f, 0.f, 0.f};

    // ---- issue B-frags for mf=1; latency hides under pass-0 compute ----
    short8 b1[8];
#pragma unroll
    for (int ks = 0; ks < 8; ++ks) {
        const int k0 = ks * 32 + lq * 8;
        const u16* p = (ks < 4) ? (Xs + (size_t)row1 * xs_stride + k0)
                                : (Xa + (size_t)row1 * 128 + (k0 - 128));
        b1[ks] = *(const short8*)p;
    }

    // ---- pass 0 (nodes w*32+0..15) ----
#pragma unroll
    for (int ks = 0; ks < 8; ++ks) {
        const int ak = ks * 32 + lq * 8;
#pragma unroll
        for (int nf = 0; nf < 8; ++nf) {
            const int jr = nf * 16 + l15;
            short8 a = *(const short8*)&WT[SWZ(jr * 256 + ak, jr)];
            acc[0][nf] = __builtin_amdgcn_mfma_f32_16x16x32_bf16(a, b0[ks], acc[0][nf], 0, 0, 0);
        }
    }
    // ---- pass 1 (nodes w*32+16..31) ----
#pragma unroll
    for (int ks = 0; ks < 8; ++ks) {
        const int ak = ks * 32 + lq * 8;
#pragma unroll
        for (int nf = 0; nf < 8; ++nf) {
            const int jr = nf * 16 + l15;
            short8 a = *(const short8*)&WT[SWZ(jr * 256 + ak, jr)];
            acc[1][nf] = __builtin_amdgcn_mfma_f32_16x16x32_bf16(a, b1[ks], acc[1][nf], 0, 0, 0);
        }
    }

    // ---- epilogue: bias + sigmoid + L2-norm; bounce via LDS (reuse WT) ----
    float4 bs4[8];
#pragma unroll
    for (int nf = 0; nf < 8; ++nf)
        bs4[nf] = *(const float4*)(bias + nf * 16 + lq * 4);

    __syncthreads();   // all WT reads complete before reuse as out-stage

#pragma unroll
    for (int mf = 0; mf < 2; ++mf) {
        const int nloc = w * 32 + mf * 16 + l15;     // this lane's node
        float h[8][4]; float ss = 0.f;
#pragma unroll
        for (int nf = 0; nf < 8; ++nf)
#pragma unroll
            for (int rg = 0; rg < 4; ++rg) {
                const float a = acc[mf][nf][rg] + bs4[nf][rg];
                const float s = 1.0f / (1.0f + __expf(-a));
                h[nf][rg] = s; ss += s * s;
            }
        ss += __shfl_xor(ss, 16); ss += __shfl_xor(ss, 32);  // across lq
        const float inv = rsqrtf(ss);
        if (MODE == 0) {
#pragma unroll
            for (int nf = 0; nf < 8; ++nf) {
                ushort4 o;
                o.x = f2bf(h[nf][0] * inv); o.y = f2bf(h[nf][1] * inv);
                o.z = f2bf(h[nf][2] * inv); o.w = f2bf(h[nf][3] * inv);
                *(ushort4*)&WT[SWZ(nloc * 128 + nf * 16 + lq * 4, nloc)] = o;
            }
        } else {
            float* OL = (float*)WT;                   // 128*128 f32 = 64KB
#pragma unroll
            for (int nf = 0; nf < 8; ++nf) {
                float4 o = make_float4(h[nf][0]*inv, h[nf][1]*inv,
                                       h[nf][2]*inv, h[nf][3]*inv);
                *(float4*)&OL[SWZF(nloc * 128 + nf * 16 + lq * 4, nloc)] = o;
            }
        }
    }
    __syncthreads();

    if (MODE == 0) {            // bf16 rows at stride 256 u16
        u16* Hb = (u16*)out_;
#pragma unroll
        for (int i = 0; i < 8; ++i) {
            int c = t + i * 256, r = c >> 4, o = c & 15, gn = block0 + r;
            if (gn < N)
                *(uint4*)(Hb + (size_t)gn * 256 + o * 8) =
                    *(const uint4*)&WT[SWZ(r * 128 + o * 8, r)];
        }
    } else {                    // fp32 dense
        float* O = (float*)out_;
        const float* OL = (const float*)WT;
#pragma unroll
        for (int i = 0; i < 16; ++i) {
            int c = t + i * 256, r = c >> 5, o = c & 31, gn = block0 + r;
            if (gn < N)
                *(float4*)(O + (size_t)gn * D + o * 4) =
                    *(const float4*)&OL[SWZF(r * 128 + o * 4, r)];
        }
    }
}

// ---------------------------------------------------------------------------
// ws layout (51.2MB total, proven footprint):
//   Zb  [0, 25.6M)      : convert_z -> gemm0 (live through gemm0)
//   XA0 [25.6M, 51.2M)  : gather25 -> gemm0
//   XA1 [0, 25.6M)      : gather10 -> gemm1 (overlays dead Zb)
// W transposed in-kernel -> no ws regions for W0T/W1T, no transpose kernels.
// Hb (bf16, 512B-stride rows) lives in d_out; gemm1 overwrites in place.
// ---------------------------------------------------------------------------
extern "C" void kernel_launch(void* const* d_in, const int* in_sizes, int n_in,
                              void* d_out, int out_size, void* d_ws, size_t ws_size,
                              hipStream_t stream) {
    const float* Z  = (const float*)d_in[0];
    const float* W0 = (const float*)d_in[1];
    const float* b0 = (const float*)d_in[2];
    const float* W1 = (const float*)d_in[3];
    const float* b1 = (const float*)d_in[4];
    const int*   n0 = (const int*)d_in[5];
    const int*   n1 = (const int*)d_in[6];
    const int N = in_sizes[0] / D;                     // 100000

    const size_t zbBytes = (size_t)N * D * 2;          // 25.6 MB
    u16* Zb  = (u16*)d_ws;
    u16* XA0 = (u16*)((char*)d_ws + zbBytes);
    u16* XA1 = (u16*)d_ws;
    u16* Hb  = (u16*)d_out;

    const int n4 = (N * D) / 4;
    const int cvtBlocks    = (n4 + 255) / 256;
    const int gatherBlocks = (N + 3) / 4;
    const int gemmBlocks   = (N + 127) / 128;

    convert_z<<<cvtBlocks, 256, 0, stream>>>((const float4*)Z, (ushort4*)Zb, n4);
    sage_gather_b<25><<<gatherBlocks, 256, 0, stream>>>(Zb, 128, n0, XA0, N);
    sage_gemm_mfma<0><<<gemmBlocks, 256, 0, stream>>>(Zb, 128, XA0, W0, b0, (void*)Hb, N);
    sage_gather_b<10><<<gatherBlocks, 256, 0, stream>>>(Hb, 256, n1, XA1, N);
    sage_gemm_mfma<1><<<gemmBlocks, 256, 0, stream>>>(Hb, 256, XA1, W1, b1, d_out, N);
}